// Round 15
// baseline (111.941 us; speedup 1.0000x reference)
//
#include <hip/hip_runtime.h>

// RelativeMultiHeadAttn: B=8 S=512 D_MODEL=1024 H=16 HD=64
// Round 14: k_attn occupancy push — QBLK=64 (grid 1024), V-frags direct
//           from global (issue-early, no Vt staging), LDS 51.4 KB ->
//           3 blocks/CU (12 waves). Softmax/staging = R11 (best, passed).
//           gemm/prep = R10-13 (passed).
//   ws layout (bytes):
//     xh   @ 0MiB  : x cast to fp16             [4096][1024]  (8 MiB)
//     wT   @ 8MiB  : Wqv transposed fp16        [2048][1024]  (4 MiB)
//     posP @ 12MiB : [sin(t f), cos(t f)] fp16  [512][64]     (64 KiB)
//     qrr  @ 13MiB : (q + r_r_bias)*log2e fp16  [B,H,S,64]    (8 MiB)
//     qrwp @ 21MiB : rot(q + r_w_bias)*log2e    [B,H,S,64]    (8 MiB)
//     vT   @ 29MiB : v transposed fp16          [B,H,64,S]    (8 MiB)

using h4 = __attribute__((ext_vector_type(4))) _Float16;
using h8 = __attribute__((ext_vector_type(8))) _Float16;
using f32x4 = __attribute__((ext_vector_type(4))) float;

#define MFMA16(a, b, c) __builtin_amdgcn_mfma_f32_16x16x32_f16((a), (b), (c), 0, 0, 0)

#define GLOAD_LDS16(gp, lp)                                                        \
  __builtin_amdgcn_global_load_lds(                                                \
      (const __attribute__((address_space(1))) unsigned int*)(gp),                 \
      (__attribute__((address_space(3))) unsigned int*)(lp), 16, 0, 0)

#define L2E 1.4426950408889634f

// ---- fused prep: cast x, build posP, transpose Wqv ------------------------
__global__ __launch_bounds__(256) void k_prep(const float* __restrict__ x,
                                              const float* __restrict__ Wqv,
                                              _Float16* __restrict__ xh,
                                              _Float16* __restrict__ wT,
                                              _Float16* __restrict__ posP) {
  __shared__ _Float16 t[64][72];
  int bid = blockIdx.x;
  int tid = threadIdx.x;
  if (bid < 2048) {
    size_t idx = (size_t)bid * 256 + tid;
    const float* src = x + idx * 8;
    _Float16 tmp[8];
#pragma unroll
    for (int j = 0; j < 8; ++j) tmp[j] = (_Float16)src[j];
    *(h8*)(xh + idx * 8) = *(const h8*)tmp;
  } else if (bid < 2176) {
    int idx = (bid - 2048) * 256 + tid;
    int tt = idx >> 6, j = idx & 63;
    int jj = j & 31;
    float f = expf((float)jj * (-9.210340371976184f / 31.0f));  // 10000^(-jj/31)
    float ang = (float)tt * f;
    posP[idx] = (_Float16)((j < 32) ? sinf(ang) : cosf(ang));
  } else {
    int b2 = bid - 2176;
    int bk = b2 & 15, bn = b2 >> 4;
    int k0 = bk * 64, n0 = bn * 64;
    int r = tid >> 2, c = (tid & 3) * 16;
    const float* src = Wqv + (size_t)(k0 + r) * 2048 + n0 + c;
#pragma unroll
    for (int j = 0; j < 16; ++j) t[r][c + j] = (_Float16)src[j];
    __syncthreads();
    _Float16 tmp[16];
#pragma unroll
    for (int j = 0; j < 16; ++j) tmp[j] = t[c + j][r];
    _Float16* dst = wT + (size_t)(n0 + r) * 1024 + k0 + c;
    *(h8*)dst = *(const h8*)tmp;
    *(h8*)(dst + 8) = *(const h8*)(tmp + 8);
  }
}

// ---- GEMM qv = x @ Wqv, 128x128x64, double-buffered, XOR-swizzled LDS -----
__global__ __launch_bounds__(256) void k_gemm(const _Float16* __restrict__ xh,
                                              const _Float16* __restrict__ wT,
                                              const float* __restrict__ rr,
                                              const float* __restrict__ rw,
                                              _Float16* __restrict__ qrr,
                                              _Float16* __restrict__ qrwp,
                                              _Float16* __restrict__ vT) {
  __shared__ _Float16 At[2][128 * 64];  // 2 x 16 KiB
  __shared__ _Float16 Bt[2][128 * 64];  // 2 x 16 KiB

  int bid = blockIdx.x;
  int bm = bid & 31, bn = bid >> 5;
  int tid = threadIdx.x;
  int w = tid >> 6, lane = tid & 63;
  int lr = lane & 15, lg = lane >> 4;

  auto stage = [&](int bufi, int k0) {
#pragma unroll
    for (int it = 0; it < 4; ++it) {
      int a = w * 256 + it * 64 + lane;
      int trow = a >> 3, c8s = (a & 7) ^ (trow & 7);
      GLOAD_LDS16(xh + (size_t)(bm * 128 + trow) * 1024 + k0 + c8s * 8,
                  &At[bufi][a * 8]);
    }
#pragma unroll
    for (int it = 0; it < 4; ++it) {
      int a = w * 256 + it * 64 + lane;
      int trow = a >> 3, c8s = (a & 7) ^ (trow & 7);
      GLOAD_LDS16(wT + (size_t)(bn * 128 + trow) * 1024 + k0 + c8s * 8,
                  &Bt[bufi][a * 8]);
    }
  };

  int wm = w >> 1, wn = w & 1;
  f32x4 acc[4][4] = {};

  stage(0, 0);
  __syncthreads();
  int buf = 0;
  for (int i = 0; i < 16; ++i) {
    if (i < 15) stage(buf ^ 1, (i + 1) * 64);
#pragma unroll
    for (int kk = 0; kk < 2; ++kk) {
      h8 af[4], bf[4];
#pragma unroll
      for (int mi = 0; mi < 4; ++mi) {
        int row = wm * 64 + mi * 16 + lr;
        af[mi] = *(const h8*)(&At[buf][row * 64 + (((kk * 4 + lg) ^ (lr & 7)) * 8)]);
      }
#pragma unroll
      for (int ni = 0; ni < 4; ++ni) {
        int row = wn * 64 + ni * 16 + lr;
        bf[ni] = *(const h8*)(&Bt[buf][row * 64 + (((kk * 4 + lg) ^ (lr & 7)) * 8)]);
      }
#pragma unroll
      for (int mi = 0; mi < 4; ++mi)
#pragma unroll
        for (int ni = 0; ni < 4; ++ni)
          acc[mi][ni] = MFMA16(af[mi], bf[ni], acc[mi][ni]);
    }
    __syncthreads();
    buf ^= 1;
  }

  int hg = bn * 2 + wn;
  int mb = bm * 128 + wm * 64;
  if (hg < 16) {
    int h = hg;
    float rrv[4], rwv[4];
#pragma unroll
    for (int ni = 0; ni < 4; ++ni) {
      rrv[ni] = rr[h * 64 + ni * 16 + lr];
      rwv[ni] = rw[h * 64 + ni * 16 + lr];
    }
    float f0 = expf((float)lr * (-9.210340371976184f / 31.0f));
    float f1 = expf((float)(16 + lr) * (-9.210340371976184f / 31.0f));
#pragma unroll
    for (int mi = 0; mi < 4; ++mi)
#pragma unroll
      for (int r = 0; r < 4; ++r) {
        int m = mb + mi * 16 + lg * 4 + r;
        int b = m >> 9, s = m & 511;
        size_t base = ((size_t)(b * 16 + h) * 512 + s) * 64;
#pragma unroll
        for (int ni = 0; ni < 4; ++ni)
          qrr[base + ni * 16 + lr] = (_Float16)((acc[mi][ni][r] + rrv[ni]) * L2E);
        {
          float qs = acc[mi][0][r] + rwv[0], qc = acc[mi][2][r] + rwv[2];
          float sn, cs;
          __sincosf((float)s * f0, &sn, &cs);
          qrwp[base + lr] = (_Float16)((qs * cs + qc * sn) * L2E);
          qrwp[base + lr + 32] = (_Float16)((qc * cs - qs * sn) * L2E);
        }
        {
          float qs = acc[mi][1][r] + rwv[1], qc = acc[mi][3][r] + rwv[3];
          float sn, cs;
          __sincosf((float)s * f1, &sn, &cs);
          qrwp[base + 16 + lr] = (_Float16)((qs * cs + qc * sn) * L2E);
          qrwp[base + 16 + lr + 32] = (_Float16)((qc * cs - qs * sn) * L2E);
        }
      }
  } else {
    int h = hg - 16;
#pragma unroll
    for (int mi = 0; mi < 4; ++mi) {
      int m = mb + mi * 16 + lg * 4;
      int b = m >> 9, s0 = m & 511;
      size_t vtbase = (size_t)(b * 16 + h) * 64 * 512;
#pragma unroll
      for (int ni = 0; ni < 4; ++ni) {
        int d = ni * 16 + lr;
        _Float16 t4[4];
#pragma unroll
        for (int r = 0; r < 4; ++r) t4[r] = (_Float16)acc[mi][ni][r];
        *(h4*)(vT + vtbase + (size_t)d * 512 + s0) = *(const h4*)t4;
      }
    }
  }
}

// ---- flash attention: one block per (b, h, 64-row q-block) ----------------
// Decode: qb = bid>>7 -> all 8 q-blocks of one (b,h) share bid mod 8 (XCD).
// Per 128-wide KV tile: stage Kp[128][128]=[K|posP] to LDS (32 KiB); V-frags
// loaded DIRECTLY global->reg right after the barrier (issue-early, consumed
// in PV after scores+softmax -> latency hidden; vT is XCD-local L2-hot).
// LDS 51.4 KiB -> 3 blocks/CU (12 waves). Swapped-QK softmax = R11.
__global__ __launch_bounds__(256, 3) void k_attn(const _Float16* __restrict__ xh,
                                                 const _Float16* __restrict__ qrr,
                                                 const _Float16* __restrict__ qrwp,
                                                 const _Float16* __restrict__ vT,
                                                 const _Float16* __restrict__ posPg,
                                                 const int* __restrict__ mask,
                                                 float* __restrict__ out) {
  __shared__ _Float16 Kp[128 * 128];    // [t][K(0:64)|posP(0:64)]  32 KiB
  __shared__ _Float16 Pl[4][16 * 136];  // per-wave P strip        17.4 KiB
  __shared__ float Ma[512];             // additive mask (log2e-scaled) 2 KiB

  int bid = blockIdx.x;
  int qb = bid >> 7, h = bid & 15, b = (bid >> 4) & 7;
  int q0 = qb * 64;
  int tid = threadIdx.x;
  int w = tid >> 6, lane = tid & 63;
  int lr = lane & 15, lg = lane >> 4;

  const size_t bh = (size_t)(b * 16 + h);
  const _Float16* kb = xh + (size_t)b * 512 * 1024 + h * 64;
  const _Float16* vTp = vT + bh * 64 * 512;
  const int* mrow = mask + b * 512;

  // stage one 128-wide [K|posP] tile: 2048 16B chunks, 8 per wave-iter
  auto stage = [&](int t0s) {
#pragma unroll
    for (int it = 0; it < 8; ++it) {
      int a = w * 512 + it * 64 + lane;
      int trow = a >> 4, c16 = a & 15;
      int c16s = c16 ^ (trow & 15);
      const _Float16* g = (c16s < 8)
          ? kb + (size_t)(t0s + trow) * 1024 + c16s * 8
          : posPg + (size_t)(t0s + trow) * 64 + (c16s - 8) * 8;
      GLOAD_LDS16(g, &Kp[(size_t)(w * 512 + it * 64) * 8]);
    }
  };

  Ma[tid] = (1.f - (float)mrow[tid]) * -1.4426950e8f;
  Ma[tid + 256] = (1.f - (float)mrow[tid + 256]) * -1.4426950e8f;

  // Hoist Q-fragments (rows q0 + 16w + lr).
  const _Float16* qrr_p = qrr + (bh * 512 + q0 + 16 * w + lr) * 64 + lg * 8;
  const _Float16* qrw_p = qrwp + (bh * 512 + q0 + 16 * w + lr) * 64 + lg * 8;
  h8 ar0 = *(const h8*)(qrr_p);
  h8 ar1 = *(const h8*)(qrr_p + 32);
  h8 aw0 = *(const h8*)(qrw_p);
  h8 aw1 = *(const h8*)(qrw_p + 32);

  float m_run = -1e30f, l_run = 0.f;
  f32x4 O[4];
#pragma unroll
  for (int df = 0; df < 4; ++df) O[df] = (f32x4){0.f, 0.f, 0.f, 0.f};

  _Float16* pw = &Pl[w][0];

  for (int t0 = 0; t0 < 512; t0 += 128) {
    stage(t0);
    __syncthreads();  // drains vmcnt -> Kp tile (and Ma on first iter) ready

    // ---- V-frags global->reg, issued EARLY (consumed in PV far below) -----
    h8 vbf[4][4];
#pragma unroll
    for (int df = 0; df < 4; ++df) {
      const _Float16* vp = vTp + (size_t)(df * 16 + lr) * 512 + t0 + lg * 8;
#pragma unroll
      for (int ks = 0; ks < 4; ++ks) vbf[df][ks] = *(const h8*)(vp + ks * 32);
    }

    // ---- scores SWAPPED: s[tf][r] = S[t = t0+tf*16+lg*4+r][q = lr] --------
    float s[8][4];
    __builtin_amdgcn_s_setprio(1);
#pragma unroll
    for (int tf = 0; tf < 8; ++tf) {
      int row = tf * 16 + lr;  // row & 15 == lr
      const _Float16* bp = &Kp[row * 128];
      h8 b0 = *(const h8*)(bp + ((0 + lg) ^ lr) * 8);
      h8 b1 = *(const h8*)(bp + ((4 + lg) ^ lr) * 8);
      h8 b2 = *(const h8*)(bp + ((8 + lg) ^ lr) * 8);
      h8 b3 = *(const h8*)(bp + ((12 + lg) ^ lr) * 8);
      f32x4 c = {0.f, 0.f, 0.f, 0.f};
      c = MFMA16(b0, ar0, c);  // A = K-rows (t), B = Q-rows (q)
      c = MFMA16(b1, ar1, c);
      c = MFMA16(b2, aw0, c);
      c = MFMA16(b3, aw1, c);
      f32x4 mav = *(const f32x4*)&Ma[t0 + tf * 16 + lg * 4];
#pragma unroll
      for (int r = 0; r < 4; ++r) s[tf][r] = c[r] + mav[r];
    }
    __builtin_amdgcn_s_setprio(0);

    // ---- softmax (q = lr lane-local): in-lane trees + 2 cross-lg shfl -----
    float rm = s[0][0];
#pragma unroll
    for (int tf = 0; tf < 8; ++tf)
#pragma unroll
      for (int r = 0; r < 4; ++r) rm = fmaxf(rm, s[tf][r]);
    rm = fmaxf(rm, __shfl_xor(rm, 16));
    rm = fmaxf(rm, __shfl_xor(rm, 32));

    if (!__all(rm - m_run <= 8.f)) {  // defer-max (THR=8, log2 space)
      float mn = fmaxf(m_run, rm);
      float sc = exp2f(m_run - mn);
      m_run = mn;
      l_run *= sc;
      float scq[4];
#pragma unroll
      for (int r = 0; r < 4; ++r) scq[r] = __shfl(sc, lg * 4 + r);
#pragma unroll
      for (int df = 0; df < 4; ++df)
#pragma unroll
        for (int r = 0; r < 4; ++r) O[df][r] *= scq[r];
    }

    float rs = 0.f;
#pragma unroll
    for (int tf = 0; tf < 8; ++tf) {
      _Float16 p4[4];
#pragma unroll
      for (int r = 0; r < 4; ++r) {
        float p = exp2f(s[tf][r] - m_run);
        p4[r] = (_Float16)p;
        rs += (float)p4[r];  // accumulate rounded value for PV consistency
      }
      *(h4*)(pw + lr * 136 + tf * 16 + lg * 4) = *(const h4*)p4;  // b64
    }
    rs += __shfl_xor(rs, 16);
    rs += __shfl_xor(rs, 32);
    l_run += rs;

    // ---- PV: P (wave-private strip, same-wave in-order) as A; V from regs -
    h8 pa[4];
#pragma unroll
    for (int ks = 0; ks < 4; ++ks)
      pa[ks] = *(const h8*)(pw + lr * 136 + ks * 32 + lg * 8);
    __builtin_amdgcn_s_setprio(1);
#pragma unroll
    for (int df = 0; df < 4; ++df)
#pragma unroll
      for (int ks = 0; ks < 4; ++ks)
        O[df] = MFMA16(pa[ks], vbf[df][ks], O[df]);
    __builtin_amdgcn_s_setprio(0);

    __syncthreads();  // all Kp reads done before next tile's staging
  }

  // ---- epilogue: broadcast l to O layout, normalize, store
  float lq[4];
#pragma unroll
  for (int r = 0; r < 4; ++r) lq[r] = __shfl(l_run, lg * 4 + r);
#pragma unroll
  for (int df = 0; df < 4; ++df)
#pragma unroll
    for (int r = 0; r < 4; ++r) {
      int ii = 16 * w + lg * 4 + r;
      out[((size_t)b * 512 + q0 + ii) * 1024 + h * 64 + df * 16 + lr] =
          O[df][r] / lq[r];
    }
}

extern "C" void kernel_launch(void* const* d_in, const int* in_sizes, int n_in,
                              void* d_out, int out_size, void* d_ws, size_t ws_size,
                              hipStream_t stream) {
  const float* x = (const float*)d_in[0];
  const int* mask = (const int*)d_in[1];
  const float* Wqv = (const float*)d_in[2];
  const float* rr = (const float*)d_in[3];
  const float* rw = (const float*)d_in[4];
  float* out = (float*)d_out;
  char* ws = (char*)d_ws;
  const size_t MB = 1024 * 1024;
  _Float16* xh = (_Float16*)(ws);
  _Float16* wT = (_Float16*)(ws + 8 * MB);
  _Float16* posP = (_Float16*)(ws + 12 * MB);
  _Float16* qrr = (_Float16*)(ws + 13 * MB);
  _Float16* qrwp = (_Float16*)(ws + 21 * MB);
  _Float16* vT = (_Float16*)(ws + 29 * MB);

  k_prep<<<2688, 256, 0, stream>>>(x, Wqv, xh, wT, posP);
  k_gemm<<<512, 256, 0, stream>>>(xh, wT, rr, rw, qrr, qrwp, vT);
  k_attn<<<1024, 256, 0, stream>>>(xh, qrr, qrwp, vT, posP, mask, out);
}

// Round 16
// 87.189 us; speedup vs baseline: 1.2839x; 1.2839x over previous
//
#include <hip/hip_runtime.h>

// RelativeMultiHeadAttn: B=8 S=512 D_MODEL=1024 H=16 HD=64
// Round 15: R14 occupancy push, spill-fixed: QBLK=64, Kp-only LDS (51 KB ->
//           3 blocks/CU), V streamed per-df in PV (4 live regs, not 16),
//           natural register allocation (no forced min-waves bound).
//           gemm/prep = R10-14 (passed).
//   ws layout (bytes):
//     xh   @ 0MiB  : x cast to fp16             [4096][1024]  (8 MiB)
//     wT   @ 8MiB  : Wqv transposed fp16        [2048][1024]  (4 MiB)
//     posP @ 12MiB : [sin(t f), cos(t f)] fp16  [512][64]     (64 KiB)
//     qrr  @ 13MiB : (q + r_r_bias)*log2e fp16  [B,H,S,64]    (8 MiB)
//     qrwp @ 21MiB : rot(q + r_w_bias)*log2e    [B,H,S,64]    (8 MiB)
//     vT   @ 29MiB : v transposed fp16          [B,H,64,S]    (8 MiB)

using h4 = __attribute__((ext_vector_type(4))) _Float16;
using h8 = __attribute__((ext_vector_type(8))) _Float16;
using f32x4 = __attribute__((ext_vector_type(4))) float;

#define MFMA16(a, b, c) __builtin_amdgcn_mfma_f32_16x16x32_f16((a), (b), (c), 0, 0, 0)

#define GLOAD_LDS16(gp, lp)                                                        \
  __builtin_amdgcn_global_load_lds(                                                \
      (const __attribute__((address_space(1))) unsigned int*)(gp),                 \
      (__attribute__((address_space(3))) unsigned int*)(lp), 16, 0, 0)

#define L2E 1.4426950408889634f

// ---- fused prep: cast x, build posP, transpose Wqv ------------------------
__global__ __launch_bounds__(256) void k_prep(const float* __restrict__ x,
                                              const float* __restrict__ Wqv,
                                              _Float16* __restrict__ xh,
                                              _Float16* __restrict__ wT,
                                              _Float16* __restrict__ posP) {
  __shared__ _Float16 t[64][72];
  int bid = blockIdx.x;
  int tid = threadIdx.x;
  if (bid < 2048) {
    size_t idx = (size_t)bid * 256 + tid;
    const float* src = x + idx * 8;
    _Float16 tmp[8];
#pragma unroll
    for (int j = 0; j < 8; ++j) tmp[j] = (_Float16)src[j];
    *(h8*)(xh + idx * 8) = *(const h8*)tmp;
  } else if (bid < 2176) {
    int idx = (bid - 2048) * 256 + tid;
    int tt = idx >> 6, j = idx & 63;
    int jj = j & 31;
    float f = expf((float)jj * (-9.210340371976184f / 31.0f));  // 10000^(-jj/31)
    float ang = (float)tt * f;
    posP[idx] = (_Float16)((j < 32) ? sinf(ang) : cosf(ang));
  } else {
    int b2 = bid - 2176;
    int bk = b2 & 15, bn = b2 >> 4;
    int k0 = bk * 64, n0 = bn * 64;
    int r = tid >> 2, c = (tid & 3) * 16;
    const float* src = Wqv + (size_t)(k0 + r) * 2048 + n0 + c;
#pragma unroll
    for (int j = 0; j < 16; ++j) t[r][c + j] = (_Float16)src[j];
    __syncthreads();
    _Float16 tmp[16];
#pragma unroll
    for (int j = 0; j < 16; ++j) tmp[j] = t[c + j][r];
    _Float16* dst = wT + (size_t)(n0 + r) * 1024 + k0 + c;
    *(h8*)dst = *(const h8*)tmp;
    *(h8*)(dst + 8) = *(const h8*)(tmp + 8);
  }
}

// ---- GEMM qv = x @ Wqv, 128x128x64, double-buffered, XOR-swizzled LDS -----
__global__ __launch_bounds__(256) void k_gemm(const _Float16* __restrict__ xh,
                                              const _Float16* __restrict__ wT,
                                              const float* __restrict__ rr,
                                              const float* __restrict__ rw,
                                              _Float16* __restrict__ qrr,
                                              _Float16* __restrict__ qrwp,
                                              _Float16* __restrict__ vT) {
  __shared__ _Float16 At[2][128 * 64];  // 2 x 16 KiB
  __shared__ _Float16 Bt[2][128 * 64];  // 2 x 16 KiB

  int bid = blockIdx.x;
  int bm = bid & 31, bn = bid >> 5;
  int tid = threadIdx.x;
  int w = tid >> 6, lane = tid & 63;
  int lr = lane & 15, lg = lane >> 4;

  auto stage = [&](int bufi, int k0) {
#pragma unroll
    for (int it = 0; it < 4; ++it) {
      int a = w * 256 + it * 64 + lane;
      int trow = a >> 3, c8s = (a & 7) ^ (trow & 7);
      GLOAD_LDS16(xh + (size_t)(bm * 128 + trow) * 1024 + k0 + c8s * 8,
                  &At[bufi][a * 8]);
    }
#pragma unroll
    for (int it = 0; it < 4; ++it) {
      int a = w * 256 + it * 64 + lane;
      int trow = a >> 3, c8s = (a & 7) ^ (trow & 7);
      GLOAD_LDS16(wT + (size_t)(bn * 128 + trow) * 1024 + k0 + c8s * 8,
                  &Bt[bufi][a * 8]);
    }
  };

  int wm = w >> 1, wn = w & 1;
  f32x4 acc[4][4] = {};

  stage(0, 0);
  __syncthreads();
  int buf = 0;
  for (int i = 0; i < 16; ++i) {
    if (i < 15) stage(buf ^ 1, (i + 1) * 64);
#pragma unroll
    for (int kk = 0; kk < 2; ++kk) {
      h8 af[4], bf[4];
#pragma unroll
      for (int mi = 0; mi < 4; ++mi) {
        int row = wm * 64 + mi * 16 + lr;
        af[mi] = *(const h8*)(&At[buf][row * 64 + (((kk * 4 + lg) ^ (lr & 7)) * 8)]);
      }
#pragma unroll
      for (int ni = 0; ni < 4; ++ni) {
        int row = wn * 64 + ni * 16 + lr;
        bf[ni] = *(const h8*)(&Bt[buf][row * 64 + (((kk * 4 + lg) ^ (lr & 7)) * 8)]);
      }
#pragma unroll
      for (int mi = 0; mi < 4; ++mi)
#pragma unroll
        for (int ni = 0; ni < 4; ++ni)
          acc[mi][ni] = MFMA16(af[mi], bf[ni], acc[mi][ni]);
    }
    __syncthreads();
    buf ^= 1;
  }

  int hg = bn * 2 + wn;
  int mb = bm * 128 + wm * 64;
  if (hg < 16) {
    int h = hg;
    float rrv[4], rwv[4];
#pragma unroll
    for (int ni = 0; ni < 4; ++ni) {
      rrv[ni] = rr[h * 64 + ni * 16 + lr];
      rwv[ni] = rw[h * 64 + ni * 16 + lr];
    }
    float f0 = expf((float)lr * (-9.210340371976184f / 31.0f));
    float f1 = expf((float)(16 + lr) * (-9.210340371976184f / 31.0f));
#pragma unroll
    for (int mi = 0; mi < 4; ++mi)
#pragma unroll
      for (int r = 0; r < 4; ++r) {
        int m = mb + mi * 16 + lg * 4 + r;
        int b = m >> 9, s = m & 511;
        size_t base = ((size_t)(b * 16 + h) * 512 + s) * 64;
#pragma unroll
        for (int ni = 0; ni < 4; ++ni)
          qrr[base + ni * 16 + lr] = (_Float16)((acc[mi][ni][r] + rrv[ni]) * L2E);
        {
          float qs = acc[mi][0][r] + rwv[0], qc = acc[mi][2][r] + rwv[2];
          float sn, cs;
          __sincosf((float)s * f0, &sn, &cs);
          qrwp[base + lr] = (_Float16)((qs * cs + qc * sn) * L2E);
          qrwp[base + lr + 32] = (_Float16)((qc * cs - qs * sn) * L2E);
        }
        {
          float qs = acc[mi][1][r] + rwv[1], qc = acc[mi][3][r] + rwv[3];
          float sn, cs;
          __sincosf((float)s * f1, &sn, &cs);
          qrwp[base + 16 + lr] = (_Float16)((qs * cs + qc * sn) * L2E);
          qrwp[base + 16 + lr + 32] = (_Float16)((qc * cs - qs * sn) * L2E);
        }
      }
  } else {
    int h = hg - 16;
#pragma unroll
    for (int mi = 0; mi < 4; ++mi) {
      int m = mb + mi * 16 + lg * 4;
      int b = m >> 9, s0 = m & 511;
      size_t vtbase = (size_t)(b * 16 + h) * 64 * 512;
#pragma unroll
      for (int ni = 0; ni < 4; ++ni) {
        int d = ni * 16 + lr;
        _Float16 t4[4];
#pragma unroll
        for (int r = 0; r < 4; ++r) t4[r] = (_Float16)acc[mi][ni][r];
        *(h4*)(vT + vtbase + (size_t)d * 512 + s0) = *(const h4*)t4;
      }
    }
  }
}

// ---- flash attention: one block per (b, h, 64-row q-block) ----------------
// Decode: qb = bid>>7 -> all 8 q-blocks of one (b,h) share bid mod 8 (XCD).
// Per 128-wide KV tile: stage Kp[128][128]=[K|posP] to LDS (32 KiB). V is
// NOT staged and NOT pre-buffered: PV streams 4 V-fragments per df from
// global (vT XCD-local, L2-hot) — only 4 h8 live at once, no spill; the
// per-df latency is covered by 12 waves/CU (3 blocks, LDS-limited).
__global__ __launch_bounds__(256) void k_attn(const _Float16* __restrict__ xh,
                                              const _Float16* __restrict__ qrr,
                                              const _Float16* __restrict__ qrwp,
                                              const _Float16* __restrict__ vT,
                                              const _Float16* __restrict__ posPg,
                                              const int* __restrict__ mask,
                                              float* __restrict__ out) {
  __shared__ _Float16 Kp[128 * 128];    // [t][K(0:64)|posP(0:64)]  32 KiB
  __shared__ _Float16 Pl[4][16 * 136];  // per-wave P strip        17.4 KiB
  __shared__ float Ma[512];             // additive mask (log2e-scaled) 2 KiB

  int bid = blockIdx.x;
  int qb = bid >> 7, h = bid & 15, b = (bid >> 4) & 7;
  int q0 = qb * 64;
  int tid = threadIdx.x;
  int w = tid >> 6, lane = tid & 63;
  int lr = lane & 15, lg = lane >> 4;

  const size_t bh = (size_t)(b * 16 + h);
  const _Float16* kb = xh + (size_t)b * 512 * 1024 + h * 64;
  const _Float16* vTp = vT + bh * 64 * 512;
  const int* mrow = mask + b * 512;

  // stage one 128-wide [K|posP] tile: 2048 16B chunks, 8 per wave-iter
  auto stage = [&](int t0s) {
#pragma unroll
    for (int it = 0; it < 8; ++it) {
      int a = w * 512 + it * 64 + lane;
      int trow = a >> 4, c16 = a & 15;
      int c16s = c16 ^ (trow & 15);
      const _Float16* g = (c16s < 8)
          ? kb + (size_t)(t0s + trow) * 1024 + c16s * 8
          : posPg + (size_t)(t0s + trow) * 64 + (c16s - 8) * 8;
      GLOAD_LDS16(g, &Kp[(size_t)(w * 512 + it * 64) * 8]);
    }
  };

  Ma[tid] = (1.f - (float)mrow[tid]) * -1.4426950e8f;
  Ma[tid + 256] = (1.f - (float)mrow[tid + 256]) * -1.4426950e8f;

  // Hoist Q-fragments (rows q0 + 16w + lr).
  const _Float16* qrr_p = qrr + (bh * 512 + q0 + 16 * w + lr) * 64 + lg * 8;
  const _Float16* qrw_p = qrwp + (bh * 512 + q0 + 16 * w + lr) * 64 + lg * 8;
  h8 ar0 = *(const h8*)(qrr_p);
  h8 ar1 = *(const h8*)(qrr_p + 32);
  h8 aw0 = *(const h8*)(qrw_p);
  h8 aw1 = *(const h8*)(qrw_p + 32);

  float m_run = -1e30f, l_run = 0.f;
  f32x4 O[4];
#pragma unroll
  for (int df = 0; df < 4; ++df) O[df] = (f32x4){0.f, 0.f, 0.f, 0.f};

  _Float16* pw = &Pl[w][0];

  for (int t0 = 0; t0 < 512; t0 += 128) {
    stage(t0);
    __syncthreads();  // drains vmcnt -> Kp tile (and Ma on first iter) ready

    // ---- scores SWAPPED: s[tf][r] = S[t = t0+tf*16+lg*4+r][q = lr] --------
    float s[8][4];
    __builtin_amdgcn_s_setprio(1);
#pragma unroll
    for (int tf = 0; tf < 8; ++tf) {
      int row = tf * 16 + lr;  // row & 15 == lr
      const _Float16* bp = &Kp[row * 128];
      h8 b0 = *(const h8*)(bp + ((0 + lg) ^ lr) * 8);
      h8 b1 = *(const h8*)(bp + ((4 + lg) ^ lr) * 8);
      h8 b2 = *(const h8*)(bp + ((8 + lg) ^ lr) * 8);
      h8 b3 = *(const h8*)(bp + ((12 + lg) ^ lr) * 8);
      f32x4 c = {0.f, 0.f, 0.f, 0.f};
      c = MFMA16(b0, ar0, c);  // A = K-rows (t), B = Q-rows (q)
      c = MFMA16(b1, ar1, c);
      c = MFMA16(b2, aw0, c);
      c = MFMA16(b3, aw1, c);
      f32x4 mav = *(const f32x4*)&Ma[t0 + tf * 16 + lg * 4];
#pragma unroll
      for (int r = 0; r < 4; ++r) s[tf][r] = c[r] + mav[r];
    }
    __builtin_amdgcn_s_setprio(0);

    // ---- softmax (q = lr lane-local): in-lane trees + 2 cross-lg shfl -----
    float rm = s[0][0];
#pragma unroll
    for (int tf = 0; tf < 8; ++tf)
#pragma unroll
      for (int r = 0; r < 4; ++r) rm = fmaxf(rm, s[tf][r]);
    rm = fmaxf(rm, __shfl_xor(rm, 16));
    rm = fmaxf(rm, __shfl_xor(rm, 32));

    if (!__all(rm - m_run <= 8.f)) {  // defer-max (THR=8, log2 space)
      float mn = fmaxf(m_run, rm);
      float sc = exp2f(m_run - mn);
      m_run = mn;
      l_run *= sc;
      float scq[4];
#pragma unroll
      for (int r = 0; r < 4; ++r) scq[r] = __shfl(sc, lg * 4 + r);
#pragma unroll
      for (int df = 0; df < 4; ++df)
#pragma unroll
        for (int r = 0; r < 4; ++r) O[df][r] *= scq[r];
    }

    float rs = 0.f;
#pragma unroll
    for (int tf = 0; tf < 8; ++tf) {
      _Float16 p4[4];
#pragma unroll
      for (int r = 0; r < 4; ++r) {
        float p = exp2f(s[tf][r] - m_run);
        p4[r] = (_Float16)p;
        rs += (float)p4[r];  // accumulate rounded value for PV consistency
      }
      *(h4*)(pw + lr * 136 + tf * 16 + lg * 4) = *(const h4*)p4;  // b64
    }
    rs += __shfl_xor(rs, 16);
    rs += __shfl_xor(rs, 32);
    l_run += rs;

    // ---- PV: P (wave-private strip) as A; V streamed per-df from global ---
    h8 pa[4];
#pragma unroll
    for (int ks = 0; ks < 4; ++ks)
      pa[ks] = *(const h8*)(pw + lr * 136 + ks * 32 + lg * 8);
#pragma unroll
    for (int df = 0; df < 4; ++df) {
      const _Float16* vp = vTp + (size_t)(df * 16 + lr) * 512 + t0 + lg * 8;
      h8 vb0 = *(const h8*)(vp);
      h8 vb1 = *(const h8*)(vp + 32);
      h8 vb2 = *(const h8*)(vp + 64);
      h8 vb3 = *(const h8*)(vp + 96);
      O[df] = MFMA16(pa[0], vb0, O[df]);
      O[df] = MFMA16(pa[1], vb1, O[df]);
      O[df] = MFMA16(pa[2], vb2, O[df]);
      O[df] = MFMA16(pa[3], vb3, O[df]);
    }

    __syncthreads();  // all Kp reads done before next tile's staging
  }

  // ---- epilogue: broadcast l to O layout, normalize, store
  float lq[4];
#pragma unroll
  for (int r = 0; r < 4; ++r) lq[r] = __shfl(l_run, lg * 4 + r);
#pragma unroll
  for (int df = 0; df < 4; ++df)
#pragma unroll
    for (int r = 0; r < 4; ++r) {
      int ii = 16 * w + lg * 4 + r;
      out[((size_t)b * 512 + q0 + ii) * 1024 + h * 64 + df * 16 + lr] =
          O[df][r] / lq[r];
    }
}

extern "C" void kernel_launch(void* const* d_in, const int* in_sizes, int n_in,
                              void* d_out, int out_size, void* d_ws, size_t ws_size,
                              hipStream_t stream) {
  const float* x = (const float*)d_in[0];
  const int* mask = (const int*)d_in[1];
  const float* Wqv = (const float*)d_in[2];
  const float* rr = (const float*)d_in[3];
  const float* rw = (const float*)d_in[4];
  float* out = (float*)d_out;
  char* ws = (char*)d_ws;
  const size_t MB = 1024 * 1024;
  _Float16* xh = (_Float16*)(ws);
  _Float16* wT = (_Float16*)(ws + 8 * MB);
  _Float16* posP = (_Float16*)(ws + 12 * MB);
  _Float16* qrr = (_Float16*)(ws + 13 * MB);
  _Float16* qrwp = (_Float16*)(ws + 21 * MB);
  _Float16* vT = (_Float16*)(ws + 29 * MB);

  k_prep<<<2688, 256, 0, stream>>>(x, Wqv, xh, wT, posP);
  k_gemm<<<512, 256, 0, stream>>>(xh, wT, rr, rw, qrr, qrwp, vT);
  k_attn<<<1024, 256, 0, stream>>>(xh, qrr, qrwp, vT, posP, mask, out);
}

// Round 17
// 67.734 us; speedup vs baseline: 1.6527x; 1.2872x over previous
//
#include <hip/hip_runtime.h>

// RelativeMultiHeadAttn: B=8 S=512 D_MODEL=1024 H=16 HD=64
// Round 16: exact revert to Round 11 (best measured: 68.0 us).
//   k_attn: QBLK=128 (2 rg), staged Kp=[K|posP]+Vt per 128-wide tile,
//           swapped QK^T (S[t][q], q lane-local), in-lane softmax,
//           defer-max THR=8 (log2 space), exp2, setprio.
//   k_gemm: 128x128x64 dbuf, XOR-swizzled LDS, __sincosf rotation epilogue.
//   ws layout (bytes):
//     xh   @ 0MiB  : x cast to fp16             [4096][1024]  (8 MiB)
//     wT   @ 8MiB  : Wqv transposed fp16        [2048][1024]  (4 MiB)
//     posP @ 12MiB : [sin(t f), cos(t f)] fp16  [512][64]     (64 KiB)
//     qrr  @ 13MiB : (q + r_r_bias)*log2e fp16  [B,H,S,64]    (8 MiB)
//     qrwp @ 21MiB : rot(q + r_w_bias)*log2e    [B,H,S,64]    (8 MiB)
//     vT   @ 29MiB : v transposed fp16          [B,H,64,S]    (8 MiB)

using h4 = __attribute__((ext_vector_type(4))) _Float16;
using h8 = __attribute__((ext_vector_type(8))) _Float16;
using f32x4 = __attribute__((ext_vector_type(4))) float;

#define MFMA16(a, b, c) __builtin_amdgcn_mfma_f32_16x16x32_f16((a), (b), (c), 0, 0, 0)

#define GLOAD_LDS16(gp, lp)                                                        \
  __builtin_amdgcn_global_load_lds(                                                \
      (const __attribute__((address_space(1))) unsigned int*)(gp),                 \
      (__attribute__((address_space(3))) unsigned int*)(lp), 16, 0, 0)

#define L2E 1.4426950408889634f

// ---- fused prep: cast x, build posP, transpose Wqv ------------------------
__global__ __launch_bounds__(256) void k_prep(const float* __restrict__ x,
                                              const float* __restrict__ Wqv,
                                              _Float16* __restrict__ xh,
                                              _Float16* __restrict__ wT,
                                              _Float16* __restrict__ posP) {
  __shared__ _Float16 t[64][72];
  int bid = blockIdx.x;
  int tid = threadIdx.x;
  if (bid < 2048) {
    size_t idx = (size_t)bid * 256 + tid;
    const float* src = x + idx * 8;
    _Float16 tmp[8];
#pragma unroll
    for (int j = 0; j < 8; ++j) tmp[j] = (_Float16)src[j];
    *(h8*)(xh + idx * 8) = *(const h8*)tmp;
  } else if (bid < 2176) {
    int idx = (bid - 2048) * 256 + tid;
    int tt = idx >> 6, j = idx & 63;
    int jj = j & 31;
    float f = expf((float)jj * (-9.210340371976184f / 31.0f));  // 10000^(-jj/31)
    float ang = (float)tt * f;
    posP[idx] = (_Float16)((j < 32) ? sinf(ang) : cosf(ang));
  } else {
    int b2 = bid - 2176;
    int bk = b2 & 15, bn = b2 >> 4;
    int k0 = bk * 64, n0 = bn * 64;
    int r = tid >> 2, c = (tid & 3) * 16;
    const float* src = Wqv + (size_t)(k0 + r) * 2048 + n0 + c;
#pragma unroll
    for (int j = 0; j < 16; ++j) t[r][c + j] = (_Float16)src[j];
    __syncthreads();
    _Float16 tmp[16];
#pragma unroll
    for (int j = 0; j < 16; ++j) tmp[j] = t[c + j][r];
    _Float16* dst = wT + (size_t)(n0 + r) * 1024 + k0 + c;
    *(h8*)dst = *(const h8*)tmp;
    *(h8*)(dst + 8) = *(const h8*)(tmp + 8);
  }
}

// ---- GEMM qv = x @ Wqv, 128x128x64, double-buffered, XOR-swizzled LDS -----
__global__ __launch_bounds__(256) void k_gemm(const _Float16* __restrict__ xh,
                                              const _Float16* __restrict__ wT,
                                              const float* __restrict__ rr,
                                              const float* __restrict__ rw,
                                              _Float16* __restrict__ qrr,
                                              _Float16* __restrict__ qrwp,
                                              _Float16* __restrict__ vT) {
  __shared__ _Float16 At[2][128 * 64];  // 2 x 16 KiB
  __shared__ _Float16 Bt[2][128 * 64];  // 2 x 16 KiB

  int bid = blockIdx.x;
  int bm = bid & 31, bn = bid >> 5;
  int tid = threadIdx.x;
  int w = tid >> 6, lane = tid & 63;
  int lr = lane & 15, lg = lane >> 4;

  auto stage = [&](int bufi, int k0) {
#pragma unroll
    for (int it = 0; it < 4; ++it) {
      int a = w * 256 + it * 64 + lane;
      int trow = a >> 3, c8s = (a & 7) ^ (trow & 7);
      GLOAD_LDS16(xh + (size_t)(bm * 128 + trow) * 1024 + k0 + c8s * 8,
                  &At[bufi][a * 8]);
    }
#pragma unroll
    for (int it = 0; it < 4; ++it) {
      int a = w * 256 + it * 64 + lane;
      int trow = a >> 3, c8s = (a & 7) ^ (trow & 7);
      GLOAD_LDS16(wT + (size_t)(bn * 128 + trow) * 1024 + k0 + c8s * 8,
                  &Bt[bufi][a * 8]);
    }
  };

  int wm = w >> 1, wn = w & 1;
  f32x4 acc[4][4] = {};

  stage(0, 0);
  __syncthreads();
  int buf = 0;
  for (int i = 0; i < 16; ++i) {
    if (i < 15) stage(buf ^ 1, (i + 1) * 64);
#pragma unroll
    for (int kk = 0; kk < 2; ++kk) {
      h8 af[4], bf[4];
#pragma unroll
      for (int mi = 0; mi < 4; ++mi) {
        int row = wm * 64 + mi * 16 + lr;
        af[mi] = *(const h8*)(&At[buf][row * 64 + (((kk * 4 + lg) ^ (lr & 7)) * 8)]);
      }
#pragma unroll
      for (int ni = 0; ni < 4; ++ni) {
        int row = wn * 64 + ni * 16 + lr;
        bf[ni] = *(const h8*)(&Bt[buf][row * 64 + (((kk * 4 + lg) ^ (lr & 7)) * 8)]);
      }
#pragma unroll
      for (int mi = 0; mi < 4; ++mi)
#pragma unroll
        for (int ni = 0; ni < 4; ++ni)
          acc[mi][ni] = MFMA16(af[mi], bf[ni], acc[mi][ni]);
    }
    __syncthreads();
    buf ^= 1;
  }

  int hg = bn * 2 + wn;
  int mb = bm * 128 + wm * 64;
  if (hg < 16) {
    int h = hg;
    float rrv[4], rwv[4];
#pragma unroll
    for (int ni = 0; ni < 4; ++ni) {
      rrv[ni] = rr[h * 64 + ni * 16 + lr];
      rwv[ni] = rw[h * 64 + ni * 16 + lr];
    }
    float f0 = expf((float)lr * (-9.210340371976184f / 31.0f));
    float f1 = expf((float)(16 + lr) * (-9.210340371976184f / 31.0f));
#pragma unroll
    for (int mi = 0; mi < 4; ++mi)
#pragma unroll
      for (int r = 0; r < 4; ++r) {
        int m = mb + mi * 16 + lg * 4 + r;
        int b = m >> 9, s = m & 511;
        size_t base = ((size_t)(b * 16 + h) * 512 + s) * 64;
#pragma unroll
        for (int ni = 0; ni < 4; ++ni)
          qrr[base + ni * 16 + lr] = (_Float16)((acc[mi][ni][r] + rrv[ni]) * L2E);
        {
          float qs = acc[mi][0][r] + rwv[0], qc = acc[mi][2][r] + rwv[2];
          float sn, cs;
          __sincosf((float)s * f0, &sn, &cs);
          qrwp[base + lr] = (_Float16)((qs * cs + qc * sn) * L2E);
          qrwp[base + lr + 32] = (_Float16)((qc * cs - qs * sn) * L2E);
        }
        {
          float qs = acc[mi][1][r] + rwv[1], qc = acc[mi][3][r] + rwv[3];
          float sn, cs;
          __sincosf((float)s * f1, &sn, &cs);
          qrwp[base + 16 + lr] = (_Float16)((qs * cs + qc * sn) * L2E);
          qrwp[base + 16 + lr + 32] = (_Float16)((qc * cs - qs * sn) * L2E);
        }
      }
  } else {
    int h = hg - 16;
#pragma unroll
    for (int mi = 0; mi < 4; ++mi) {
      int m = mb + mi * 16 + lg * 4;
      int b = m >> 9, s0 = m & 511;
      size_t vtbase = (size_t)(b * 16 + h) * 64 * 512;
#pragma unroll
      for (int ni = 0; ni < 4; ++ni) {
        int d = ni * 16 + lr;
        _Float16 t4[4];
#pragma unroll
        for (int r = 0; r < 4; ++r) t4[r] = (_Float16)acc[mi][ni][r];
        *(h4*)(vT + vtbase + (size_t)d * 512 + s0) = *(const h4*)t4;
      }
    }
  }
}

// ---- flash attention: one block per (b, h, 128-row q-block) ---------------
// Staging: per 128-wide KV tile, Kp[128][128]=[K|posP] + Vt[64][128] via
// global_load_lds (XOR-swizzled source, linear dest, swizzled reads).
// Scores SWAPPED (mfma(K_frag, Q_frag)) -> S[t][q], q = lane&15 lane-local:
// in-lane softmax trees + 2 shfl_xor; b64 P writes; defer-max THR=8.
__global__ __launch_bounds__(256, 2) void k_attn(const _Float16* __restrict__ xh,
                                                 const _Float16* __restrict__ qrr,
                                                 const _Float16* __restrict__ qrwp,
                                                 const _Float16* __restrict__ vT,
                                                 const _Float16* __restrict__ posPg,
                                                 const int* __restrict__ mask,
                                                 float* __restrict__ out) {
  __shared__ _Float16 Kp[128 * 128];    // 32 KiB
  __shared__ _Float16 Vt[64 * 128];     // 16 KiB
  __shared__ _Float16 Pl[4][16 * 136];  // per-wave P strip  17 KiB
  __shared__ float Ma[512];             // additive mask (log2e-scaled)

  int bid = blockIdx.x;
  int qb = bid >> 7, h = bid & 15, b = (bid >> 4) & 7;
  int q0 = qb * 128;
  int tid = threadIdx.x;
  int w = tid >> 6, lane = tid & 63;
  int lr = lane & 15, lg = lane >> 4;

  const size_t bh = (size_t)(b * 16 + h);
  const _Float16* kb = xh + (size_t)b * 512 * 1024 + h * 64;
  const _Float16* vTp = vT + bh * 64 * 512;
  const int* mrow = mask + b * 512;

  auto stage = [&](int t0s) {
#pragma unroll
    for (int it = 0; it < 8; ++it) {
      int a = w * 512 + it * 64 + lane;
      int trow = a >> 4, c16 = a & 15;
      int c16s = c16 ^ (trow & 15);
      const _Float16* g = (c16s < 8)
          ? kb + (size_t)(t0s + trow) * 1024 + c16s * 8
          : posPg + (size_t)(t0s + trow) * 64 + (c16s - 8) * 8;
      GLOAD_LDS16(g, &Kp[(size_t)(w * 512 + it * 64) * 8]);
    }
#pragma unroll
    for (int it = 0; it < 4; ++it) {
      int a = w * 256 + it * 64 + lane;
      int drow = a >> 4, c16 = a & 15;
      int c16s = c16 ^ (drow & 15);
      const _Float16* g = vTp + (size_t)drow * 512 + t0s + c16s * 8;
      GLOAD_LDS16(g, &Vt[(size_t)(w * 256 + it * 64) * 8]);
    }
  };

  Ma[tid] = (1.f - (float)mrow[tid]) * -1.4426950e8f;
  Ma[tid + 256] = (1.f - (float)mrow[tid + 256]) * -1.4426950e8f;

  // Hoist Q-fragments for both row groups (rows q0 + 32w + 16rg + lr).
  h8 ar0[2], ar1[2], aw0[2], aw1[2];
#pragma unroll
  for (int rg = 0; rg < 2; ++rg) {
    const _Float16* qrr_p = qrr + (bh * 512 + q0 + 32 * w + 16 * rg + lr) * 64 + lg * 8;
    const _Float16* qrw_p = qrwp + (bh * 512 + q0 + 32 * w + 16 * rg + lr) * 64 + lg * 8;
    ar0[rg] = *(const h8*)(qrr_p);
    ar1[rg] = *(const h8*)(qrr_p + 32);
    aw0[rg] = *(const h8*)(qrw_p);
    aw1[rg] = *(const h8*)(qrw_p + 32);
  }

  float m_run[2] = {-1e30f, -1e30f}, l_run[2] = {0.f, 0.f};
  f32x4 O[2][4];
#pragma unroll
  for (int rg = 0; rg < 2; ++rg)
#pragma unroll
    for (int df = 0; df < 4; ++df) O[rg][df] = (f32x4){0.f, 0.f, 0.f, 0.f};

  _Float16* pw = &Pl[w][0];

  for (int t0 = 0; t0 < 512; t0 += 128) {
    stage(t0);
    __syncthreads();  // drains vmcnt -> tile (and Ma on first iter) ready

#pragma unroll
    for (int rg = 0; rg < 2; ++rg) {
      // ---- scores SWAPPED: s[tf][r] = S[t = t0+tf*16+lg*4+r][q = lr] ------
      float s[8][4];
      __builtin_amdgcn_s_setprio(1);
#pragma unroll
      for (int tf = 0; tf < 8; ++tf) {
        int row = tf * 16 + lr;  // row & 15 == lr
        const _Float16* bp = &Kp[row * 128];
        h8 b0 = *(const h8*)(bp + ((0 + lg) ^ lr) * 8);
        h8 b1 = *(const h8*)(bp + ((4 + lg) ^ lr) * 8);
        h8 b2 = *(const h8*)(bp + ((8 + lg) ^ lr) * 8);
        h8 b3 = *(const h8*)(bp + ((12 + lg) ^ lr) * 8);
        f32x4 c = {0.f, 0.f, 0.f, 0.f};
        c = MFMA16(b0, ar0[rg], c);  // A = K-rows (t), B = Q-rows (q)
        c = MFMA16(b1, ar1[rg], c);
        c = MFMA16(b2, aw0[rg], c);
        c = MFMA16(b3, aw1[rg], c);
        f32x4 mav = *(const f32x4*)&Ma[t0 + tf * 16 + lg * 4];
#pragma unroll
        for (int r = 0; r < 4; ++r) s[tf][r] = c[r] + mav[r];
      }
      __builtin_amdgcn_s_setprio(0);

      // ---- softmax (q = lr lane-local): in-lane trees + 2 cross-lg shfl ---
      float rm = s[0][0];
#pragma unroll
      for (int tf = 0; tf < 8; ++tf)
#pragma unroll
        for (int r = 0; r < 4; ++r) rm = fmaxf(rm, s[tf][r]);
      rm = fmaxf(rm, __shfl_xor(rm, 16));
      rm = fmaxf(rm, __shfl_xor(rm, 32));

      if (!__all(rm - m_run[rg] <= 8.f)) {  // defer-max (THR=8, log2 space)
        float mn = fmaxf(m_run[rg], rm);
        float sc = exp2f(m_run[rg] - mn);
        m_run[rg] = mn;
        l_run[rg] *= sc;
        float scq[4];
#pragma unroll
        for (int r = 0; r < 4; ++r) scq[r] = __shfl(sc, lg * 4 + r);
#pragma unroll
        for (int df = 0; df < 4; ++df)
#pragma unroll
          for (int r = 0; r < 4; ++r) O[rg][df][r] *= scq[r];
      }

      float rs = 0.f;
#pragma unroll
      for (int tf = 0; tf < 8; ++tf) {
        _Float16 p4[4];
#pragma unroll
        for (int r = 0; r < 4; ++r) {
          float p = exp2f(s[tf][r] - m_run[rg]);
          p4[r] = (_Float16)p;
          rs += (float)p4[r];  // accumulate rounded value for PV consistency
        }
        *(h4*)(pw + lr * 136 + tf * 16 + lg * 4) = *(const h4*)p4;  // b64
      }
      rs += __shfl_xor(rs, 16);
      rs += __shfl_xor(rs, 32);
      l_run[rg] += rs;

      // ---- PV: P (wave-private strip, same-wave in-order) as A; V as B ----
      h8 pa[4];
#pragma unroll
      for (int ks = 0; ks < 4; ++ks)
        pa[ks] = *(const h8*)(pw + lr * 136 + ks * 32 + lg * 8);
      __builtin_amdgcn_s_setprio(1);
#pragma unroll
      for (int df = 0; df < 4; ++df) {
        int row = df * 16 + lr;  // row & 15 == lr
        const _Float16* vbp = &Vt[row * 128];
#pragma unroll
        for (int ks = 0; ks < 4; ++ks) {
          h8 vb = *(const h8*)(vbp + ((ks * 4 + lg) ^ lr) * 8);
          O[rg][df] = MFMA16(pa[ks], vb, O[rg][df]);
        }
      }
      __builtin_amdgcn_s_setprio(0);
    }
    __syncthreads();  // all LDS reads done before next tile's staging
  }

  // ---- epilogue: broadcast l to O layout, normalize, store
#pragma unroll
  for (int rg = 0; rg < 2; ++rg) {
    float lq[4];
#pragma unroll
    for (int r = 0; r < 4; ++r) lq[r] = __shfl(l_run[rg], lg * 4 + r);
#pragma unroll
    for (int df = 0; df < 4; ++df)
#pragma unroll
      for (int r = 0; r < 4; ++r) {
        int ii = 32 * w + 16 * rg + lg * 4 + r;
        out[((size_t)b * 512 + q0 + ii) * 1024 + h * 64 + df * 16 + lr] =
            O[rg][df][r] / lq[r];
      }
  }
}

extern "C" void kernel_launch(void* const* d_in, const int* in_sizes, int n_in,
                              void* d_out, int out_size, void* d_ws, size_t ws_size,
                              hipStream_t stream) {
  const float* x = (const float*)d_in[0];
  const int* mask = (const int*)d_in[1];
  const float* Wqv = (const float*)d_in[2];
  const float* rr = (const float*)d_in[3];
  const float* rw = (const float*)d_in[4];
  float* out = (float*)d_out;
  char* ws = (char*)d_ws;
  const size_t MB = 1024 * 1024;
  _Float16* xh = (_Float16*)(ws);
  _Float16* wT = (_Float16*)(ws + 8 * MB);
  _Float16* posP = (_Float16*)(ws + 12 * MB);
  _Float16* qrr = (_Float16*)(ws + 13 * MB);
  _Float16* qrwp = (_Float16*)(ws + 21 * MB);
  _Float16* vT = (_Float16*)(ws + 29 * MB);

  k_prep<<<2688, 256, 0, stream>>>(x, Wqv, xh, wT, posP);
  k_gemm<<<512, 256, 0, stream>>>(xh, wT, rr, rw, qrr, qrwp, vT);
  k_attn<<<512, 256, 0, stream>>>(xh, qrr, qrwp, vT, posP, mask, out);
}